// Round 4
// baseline (275.558 us; speedup 1.0000x reference)
//
#include <hip/hip_runtime.h>
#include <cstdint>

#define DEVI __device__ __forceinline__

typedef __bf16 bf16x8 __attribute__((ext_vector_type(8)));
typedef float  f32x4  __attribute__((ext_vector_type(4)));

DEVI unsigned short f2b(float f){
  unsigned u = __builtin_bit_cast(unsigned, f);
  unsigned r = u + 0x7FFF + ((u >> 16) & 1);
  return (unsigned short)(r >> 16);
}
DEVI float b2f(unsigned short s){
  unsigned u = ((unsigned)s) << 16;
  return __builtin_bit_cast(float, u);
}
DEVI float gelu_f(float x){
  float u = 0.7978845608028654f * (x + 0.044715f * x * x * x);
  float e = __expf(2.0f * u);
  return x * (1.0f - 1.0f / (e + 1.0f));   // == 0.5x(1+tanh(u)), safe at e->inf / e->0
}
DEVI void gl_lds16(const unsigned short* g, unsigned short* l){
  __builtin_amdgcn_global_load_lds(
      (const __attribute__((address_space(1))) unsigned int*)g,
      (__attribute__((address_space(3))) unsigned int*)l, 16, 0, 0);
}

// ---------------- weight transpose + fp32->bf16: in[R][C] f32 -> out[C][R] bf16 ----
__global__ __launch_bounds__(256)
void transpose_f2b(const float* __restrict__ in, unsigned short* __restrict__ out,
                   int R, int C)
{
  __shared__ float tile[32][33];
  int nbx = C >> 5;
  int bx = blockIdx.x % nbx, by = blockIdx.x / nbx;
  int c0 = bx << 5, r0 = by << 5;
  int tx = threadIdx.x & 31, ty = threadIdx.x >> 5;   // 32 x 8
  #pragma unroll
  for (int j = 0; j < 32; j += 8)
    tile[ty + j][tx] = in[(size_t)(r0 + ty + j) * C + c0 + tx];
  __syncthreads();
  #pragma unroll
  for (int j = 0; j < 32; j += 8)
    out[(size_t)(c0 + ty + j) * R + r0 + tx] = f2b(tile[tx][ty + j]);
}

// ---------------- RMSNorm: x f32 [rows][768] -> out bf16, 1 wave per row ----------
__global__ __launch_bounds__(256)
void rmsnorm_k(const float* __restrict__ x, const float* __restrict__ g,
               unsigned short* __restrict__ out)
{
  int wid = threadIdx.x >> 6, lane = threadIdx.x & 63;
  size_t row = (size_t)blockIdx.x * 4 + wid;
  const float* xr = x + row * 768;
  float4 v[3];
  float ss = 0.0f;
  #pragma unroll
  for (int c = 0; c < 3; c++){
    v[c] = *(const float4*)&xr[lane * 4 + c * 256];
    ss += v[c].x * v[c].x + v[c].y * v[c].y + v[c].z * v[c].z + v[c].w * v[c].w;
  }
  #pragma unroll
  for (int o = 32; o >= 1; o >>= 1) ss += __shfl_xor(ss, o);
  float rs = rsqrtf(ss * (1.0f / 768.0f) + 1e-6f);
  #pragma unroll
  for (int c = 0; c < 3; c++){
    const float4 gv = *(const float4*)&g[lane * 4 + c * 256];
    ushort4 o4;
    o4.x = f2b(v[c].x * rs * gv.x);
    o4.y = f2b(v[c].y * rs * gv.y);
    o4.z = f2b(v[c].z * rs * gv.z);
    o4.w = f2b(v[c].w * rs * gv.w);
    *(ushort4*)&out[row * 768 + lane * 4 + c * 256] = o4;
  }
}

// ---------------- GEMM 128x128 (m97 structure) for N=768 matrices ----------------
template<bool BIAS, bool GELU_, bool RES, bool OUTF32>
__global__ __launch_bounds__(256)
void gemm_bt(const unsigned short* __restrict__ A, const unsigned short* __restrict__ Bt,
             const float* __restrict__ bias, const float* __restrict__ res,
             void* __restrict__ outp, int M, int N, int K)
{
  __shared__ unsigned short As[128 * 32];
  __shared__ unsigned short Bs[128 * 32];
  int tid = threadIdx.x;
  int wid = tid >> 6, lane = tid & 63;
  int tiles_n = N >> 7;
  int bid = blockIdx.x;
  bid = (bid & 7) * (gridDim.x >> 3) + (bid >> 3);   // XCD-aware swizzle (grid % 8 == 0)
  int bm = bid / tiles_n, bn = bid % tiles_n;
  int m0 = bm << 7, n0 = bn << 7;
  int la = lane & 15, lk = lane >> 4;
  int wm = (wid >> 1) << 6, wn = (wid & 1) << 6;
  f32x4 acc[4][4] = {};

  for (int kt = 0; kt < K; kt += 32){
    #pragma unroll
    for (int i = 0; i < 2; i++){
      int wb  = i * 4096 + wid * 1024;       // byte base (wave-uniform) in tile
      int pos = wb + lane * 16;              // this lane's byte pos
      int row = pos >> 6;
      int kel = (pos & 63) >> 1;             // element offset in row
      gl_lds16(A  + (size_t)(m0 + row) * K + kt + kel, (unsigned short*)((char*)As + wb));
      gl_lds16(Bt + (size_t)(n0 + row) * K + kt + kel, (unsigned short*)((char*)Bs + wb));
    }
    __syncthreads();
    bf16x8 av[4], bv[4];
    #pragma unroll
    for (int mm = 0; mm < 4; mm++)
      av[mm] = *(const bf16x8*)&As[(wm + mm * 16 + la) * 32 + lk * 8];
    #pragma unroll
    for (int nn = 0; nn < 4; nn++)
      bv[nn] = *(const bf16x8*)&Bs[(wn + nn * 16 + la) * 32 + lk * 8];
    #pragma unroll
    for (int mm = 0; mm < 4; mm++)
      #pragma unroll
      for (int nn = 0; nn < 4; nn++)
        acc[mm][nn] = __builtin_amdgcn_mfma_f32_16x16x32_bf16(av[mm], bv[nn], acc[mm][nn], 0, 0, 0);
    __syncthreads();
  }

  float* outF = (float*)outp;
  unsigned short* outB = (unsigned short*)outp;
  #pragma unroll
  for (int mm = 0; mm < 4; mm++){
    #pragma unroll
    for (int nn = 0; nn < 4; nn++){
      #pragma unroll
      for (int r = 0; r < 4; r++){
        int row = m0 + wm + mm * 16 + lk * 4 + r;
        int col = n0 + wn + nn * 16 + la;
        float val = acc[mm][nn][r];
        if (BIAS)  val += bias[col];
        if (GELU_) val = gelu_f(val);
        if (RES)   val += res[(size_t)row * N + col];
        if (OUTF32) outF[(size_t)row * N + col] = val;
        else        outB[(size_t)row * N + col] = f2b(val);
      }
    }
  }
}

// ---------------- GEMM 256x256, BK=64, 8 waves, phased schedule + LDS swizzle -----
// C[M,N] = A[M,K] * Bt[N,K]^T. Requires M%256==0, N%256==0, K%64==0, grid%8==0.
// LDS: 2 dbuf x (A 256x64 | B 256x64) bf16 = 128 KiB, slot-XOR swizzled
// (LDS[row][slot] holds global[row][slot^(row&7)], slot = 8-elem chunk).
// Staging: all 8 global_load_lds for tile t+1 issued at tile-t start (linear dest,
// inverse-swizzled source), single vmcnt(0) drain at tile end => ~full-tile overlap.
template<bool BIAS, bool GELU_, bool OUTF32>
__global__ __launch_bounds__(512, 2)
void gemm256(const unsigned short* __restrict__ A, const unsigned short* __restrict__ Bt,
             const float* __restrict__ bias, void* __restrict__ outp,
             int M, int N, int K)
{
  __shared__ unsigned short sm[2][32768];   // [buf][ A: 0..16383 | B: 16384..32767 ]
  int tid = threadIdx.x;
  int wid = tid >> 6, lane = tid & 63;
  int la = lane & 15, hi = lane >> 4;
  int wm = wid >> 2, wn = wid & 3;          // 2 (M) x 4 (N) waves; per-wave 128x64
  int tiles_n = N >> 8;
  int bid = blockIdx.x;
  bid = (bid & 7) * (gridDim.x >> 3) + (bid >> 3);   // XCD swizzle
  int m0 = (bid / tiles_n) << 8, n0 = (bid % tiles_n) << 8;
  int NT = K >> 6;

  f32x4 acc[8][4] = {};

  // ---- prologue: stage K-tile 0 into buf 0
  #pragma unroll
  for (int l = 0; l < 4; l++){
    int wb  = (wid << 6) + l * 512;         // wave-uniform chunk index base
    int idx = wb + lane;                    // [0,2048): row=idx>>3, slot=idx&7
    int row = idx >> 3, slot = idx & 7;
    int sl2 = slot ^ (row & 7);
    gl_lds16(A  + (size_t)(m0 + row) * K + sl2 * 8, &sm[0][wb * 8]);
    gl_lds16(Bt + (size_t)(n0 + row) * K + sl2 * 8, &sm[0][16384 + wb * 8]);
  }
  asm volatile("s_waitcnt vmcnt(0)" ::: "memory");
  __builtin_amdgcn_s_barrier();

  for (int t = 0; t < NT; t++){
    int cur = t & 1;
    const unsigned short* As = sm[cur];
    const unsigned short* Bs = sm[cur] + 16384;

    // ---- front-load next tile's staging (targets dead buffer cur^1)
    if (t + 1 < NT){
      int kt = (t + 1) << 6;
      unsigned short* dst = sm[cur ^ 1];
      #pragma unroll
      for (int l = 0; l < 4; l++){
        int wb  = (wid << 6) + l * 512;
        int idx = wb + lane;
        int row = idx >> 3, slot = idx & 7;
        int sl2 = slot ^ (row & 7);
        gl_lds16(A  + (size_t)(m0 + row) * K + kt + sl2 * 8, dst + wb * 8);
        gl_lds16(Bt + (size_t)(n0 + row) * K + kt + sl2 * 8, dst + 16384 + wb * 8);
      }
    }

    // ---- B fragments for the whole K-tile (reused in all 4 phases)
    bf16x8 bfr[4][2];
    #pragma unroll
    for (int nn = 0; nn < 4; nn++)
      #pragma unroll
      for (int kk = 0; kk < 2; kk++){
        int r = wn * 64 + nn * 16 + la;
        bfr[nn][kk] = *(const bf16x8*)&Bs[r * 64 + ((kk * 4 + hi) ^ (r & 7)) * 8];
      }

    // ---- 4 phases: phase p computes m-frags {2p,2p+1} x 4 n-frags x 2 k-steps
    #pragma unroll
    for (int ph = 0; ph < 4; ph++){
      bf16x8 afr[2][2];
      #pragma unroll
      for (int mi = 0; mi < 2; mi++)
        #pragma unroll
        for (int kk = 0; kk < 2; kk++){
          int r = wm * 128 + (ph * 2 + mi) * 16 + la;
          afr[mi][kk] = *(const bf16x8*)&As[r * 64 + ((kk * 4 + hi) ^ (r & 7)) * 8];
        }
      __builtin_amdgcn_s_barrier();
      __builtin_amdgcn_s_setprio(1);
      #pragma unroll
      for (int mi = 0; mi < 2; mi++)
        #pragma unroll
        for (int nn = 0; nn < 4; nn++)
          #pragma unroll
          for (int kk = 0; kk < 2; kk++)
            acc[ph * 2 + mi][nn] = __builtin_amdgcn_mfma_f32_16x16x32_bf16(
                afr[mi][kk], bfr[nn][kk], acc[ph * 2 + mi][nn], 0, 0, 0);
      __builtin_amdgcn_s_setprio(0);
      __builtin_amdgcn_s_barrier();
    }

    // ---- tile boundary: own DMA loads landed, then join
    asm volatile("s_waitcnt vmcnt(0)" ::: "memory");
    __builtin_amdgcn_s_barrier();
  }

  // ---- epilogue
  float* outF = (float*)outp;
  unsigned short* outB = (unsigned short*)outp;
  #pragma unroll
  for (int mm = 0; mm < 8; mm++){
    int rowb = m0 + wm * 128 + mm * 16 + hi * 4;
    #pragma unroll
    for (int nn = 0; nn < 4; nn++){
      int col = n0 + wn * 64 + nn * 16 + la;
      float bv = BIAS ? bias[col] : 0.0f;
      #pragma unroll
      for (int r = 0; r < 4; r++){
        float val = acc[mm][nn][r] + bv;
        if (GELU_) val = gelu_f(val);
        size_t o = (size_t)(rowb + r) * N + col;
        if (OUTF32) outF[o] = val;
        else        outB[o] = f2b(val);
      }
    }
  }
}

// ---------------- sliding-window causal attention, W=64, D=64, MFMA tile ----------
__global__ __launch_bounds__(256)
void attn_k(const unsigned short* __restrict__ qkv, unsigned short* __restrict__ attn)
{
  __shared__ unsigned short Qs[64 * 72];       // stride 72: b128 reads at 8-way min
  __shared__ unsigned short Ks[128 * 72];
  __shared__ unsigned short Vt[64 * 136];      // V^T [d][s], stride 136
  __shared__ unsigned short Ps[4][16 * 136];   // per-wave P rows

  int tid = threadIdx.x, wid = tid >> 6, lane = tid & 63;
  int la = lane & 15, hi = lane >> 4;
  int blk = blockIdx.x;
  blk = (blk & 7) * (gridDim.x >> 3) + (blk >> 3);   // XCD swizzle (1536 % 8 == 0)
  int tile = blk & 15, hb = blk >> 4;
  int h = hb % 12, b = hb / 12;
  int t0 = tile << 6;

  const unsigned short* qbase = qkv + (size_t)(b * 1024) * 2304 + h * 64;

  // ---- stage Q: 64 rows x 8 chunks of 8 bf16
  #pragma unroll
  for (int r = 0; r < 2; r++){
    int idx = tid + r * 256;
    int row = idx >> 3, ch = idx & 7;
    uint4 v = *(const uint4*)(qbase + (size_t)(t0 + row) * 2304 + ch * 8);
    *(uint4*)&Qs[row * 72 + ch * 8] = v;
  }
  // ---- stage K: 128 rows (clamped at s_global<0; masked later)
  #pragma unroll
  for (int r = 0; r < 4; r++){
    int idx = tid + r * 256;
    int row = idx >> 3, ch = idx & 7;
    int sg = t0 - 64 + row; sg = sg < 0 ? 0 : sg;
    uint4 v = *(const uint4*)(qbase + 768 + (size_t)sg * 2304 + ch * 8);
    *(uint4*)&Ks[row * 72 + ch * 8] = v;
  }
  // ---- stage V transposed (s-major lane assignment -> 2-way LDS writes)
  #pragma unroll
  for (int r = 0; r < 4; r++){
    int idx = tid + r * 256;
    int s = idx & 127, ch = idx >> 7;
    int sg = t0 - 64 + s; sg = sg < 0 ? 0 : sg;
    uint4 v = *(const uint4*)(qbase + 1536 + (size_t)sg * 2304 + ch * 8);
    unsigned short tmp[8];
    *(uint4*)tmp = v;
    #pragma unroll
    for (int j = 0; j < 8; j++)
      Vt[(ch * 8 + j) * 136 + s] = tmp[j];
  }
  __syncthreads();

  // ---- S = Q K^T for 16 own rows x 128 cols (8 col-fragments x 2 k-steps)
  f32x4 sc[8];
  #pragma unroll
  for (int sj = 0; sj < 8; sj++) sc[sj] = (f32x4){0.f, 0.f, 0.f, 0.f};
  #pragma unroll
  for (int kk = 0; kk < 2; kk++){
    bf16x8 aq = *(const bf16x8*)&Qs[(wid * 16 + la) * 72 + kk * 32 + hi * 8];
    #pragma unroll
    for (int sj = 0; sj < 8; sj++){
      bf16x8 bk = *(const bf16x8*)&Ks[(sj * 16 + la) * 72 + kk * 32 + hi * 8];
      sc[sj] = __builtin_amdgcn_mfma_f32_16x16x32_bf16(aq, bk, sc[sj], 0, 0, 0);
    }
  }

  // ---- masked in-register softmax (row = wid*16 + hi*4 + r2, col = sj*16 + la)
  float inv[4];
  #pragma unroll
  for (int r2 = 0; r2 < 4; r2++){
    int row = wid * 16 + hi * 4 + r2;
    float mx = -1e30f;
    #pragma unroll
    for (int sj = 0; sj < 8; sj++){
      int sl = sj * 16 + la;
      bool valid = (sl >= row + 1) && (sl <= row + 64) && (t0 - 64 + sl >= 0);
      float sv = valid ? sc[sj][r2] * 0.125f : -1e30f;
      sc[sj][r2] = sv;
      mx = fmaxf(mx, sv);
    }
    #pragma unroll
    for (int o = 8; o >= 1; o >>= 1) mx = fmaxf(mx, __shfl_xor(mx, o));
    float sum = 0.0f;
    #pragma unroll
    for (int sj = 0; sj < 8; sj++){
      float p = __expf(sc[sj][r2] - mx);
      sc[sj][r2] = p;
      sum += p;
    }
    #pragma unroll
    for (int o = 8; o >= 1; o >>= 1) sum += __shfl_xor(sum, o);
    inv[r2] = 1.0f / sum;
  }

  // ---- P -> LDS (bf16), per-wave region
  unsigned short* myP = Ps[wid];
  #pragma unroll
  for (int sj = 0; sj < 8; sj++)
    #pragma unroll
    for (int r2 = 0; r2 < 4; r2++)
      myP[(hi * 4 + r2) * 136 + sj * 16 + la] = f2b(sc[sj][r2]);

  __syncthreads();

  // ---- O = P V  (A = P[16x128], B^T = Vt[64x128], 4 n-frags x 4 k-steps)
  f32x4 oacc[4];
  #pragma unroll
  for (int nj = 0; nj < 4; nj++) oacc[nj] = (f32x4){0.f, 0.f, 0.f, 0.f};
  #pragma unroll
  for (int ks = 0; ks < 4; ks++){
    bf16x8 ap = *(const bf16x8*)&myP[la * 136 + ks * 32 + hi * 8];
    #pragma unroll
    for (int nj = 0; nj < 4; nj++){
      bf16x8 bv = *(const bf16x8*)&Vt[(nj * 16 + la) * 136 + ks * 32 + hi * 8];
      oacc[nj] = __builtin_amdgcn_mfma_f32_16x16x32_bf16(ap, bv, oacc[nj], 0, 0, 0);
    }
  }

  // ---- write O (bf16, head-concat layout), scaled by 1/rowsum
  unsigned short* obase = attn + (size_t)(b * 1024 + t0) * 768 + h * 64;
  #pragma unroll
  for (int nj = 0; nj < 4; nj++)
    #pragma unroll
    for (int r2 = 0; r2 < 4; r2++){
      int row = wid * 16 + hi * 4 + r2;
      obase[(size_t)row * 768 + nj * 16 + la] = f2b(oacc[nj][r2] * inv[r2]);
    }
}

__global__ void aux_k(float* p){ if (threadIdx.x == 0) p[0] = 0.0f; }

// ----------------------------------------------------------------------------------
extern "C" void kernel_launch(void* const* d_in, const int* in_sizes, int n_in,
                              void* d_out, int out_size, void* d_ws, size_t ws_size,
                              hipStream_t stream)
{
  const float* x      = (const float*)d_in[0];
  const float* w_q    = (const float*)d_in[1];
  const float* w_k    = (const float*)d_in[2];
  const float* w_v    = (const float*)d_in[3];
  const float* w_proj = (const float*)d_in[4];
  const float* b_proj = (const float*)d_in[5];
  const float* w_ff1  = (const float*)d_in[6];
  const float* b_ff1  = (const float*)d_in[7];
  const float* w_ff2  = (const float*)d_in[8];
  const float* b_ff2  = (const float*)d_in[9];
  const float* g1     = (const float*)d_in[10];
  const float* g2     = (const float*)d_in[11];
  float* out = (float*)d_out;

  char* ws = (char*)d_ws;
  size_t off = 0;
  auto alloc = [&](size_t bytes){ size_t r = off; off += (bytes + 255) & ~(size_t)255; return r; };
  const size_t BT = 8 * 1024;  // 8192 rows

  unsigned short* h     = (unsigned short*)(ws + alloc(BT * 768 * 2));   // reused for attn out
  unsigned short* qkv   = (unsigned short*)(ws + alloc(BT * 3072 * 2));  // reused for ffa
  float*          x2    = (float*)         (ws + alloc(BT * 768 * 4));
  unsigned short* h2    = (unsigned short*)(ws + alloc(BT * 768 * 2));
  unsigned short* WqkvT = (unsigned short*)(ws + alloc(2304 * 768 * 2));
  unsigned short* WprojT= (unsigned short*)(ws + alloc(768 * 768 * 2));
  unsigned short* Wff1T = (unsigned short*)(ws + alloc(3072 * 768 * 2));
  unsigned short* Wff2T = (unsigned short*)(ws + alloc(768 * 3072 * 2));
  unsigned short* attn  = h;     // h dead after QKV GEMM
  unsigned short* ffa   = qkv;   // qkv dead after attention

  // weights -> bf16, transposed to [N][K]
  transpose_f2b<<<576, 256, 0, stream>>>(w_q,    WqkvT,             768, 768);
  transpose_f2b<<<576, 256, 0, stream>>>(w_k,    WqkvT + 768 * 768, 768, 768);
  transpose_f2b<<<576, 256, 0, stream>>>(w_v,    WqkvT + 1536 * 768,768, 768);
  transpose_f2b<<<576, 256, 0, stream>>>(w_proj, WprojT,            768, 768);
  transpose_f2b<<<24 * 96, 256, 0, stream>>>(w_ff1, Wff1T, 768, 3072);
  transpose_f2b<<<96 * 24, 256, 0, stream>>>(w_ff2, Wff2T, 3072, 768);

  // h = rmsnorm(x, g1)
  rmsnorm_k<<<2048, 256, 0, stream>>>(x, g1, h);

  // qkv = h @ [Wq|Wk|Wv]   (M=8192, N=2304, K=768), bf16 out — 256x256 schedule
  gemm256<false,false,false><<<32 * 9, 512, 0, stream>>>(h, WqkvT, nullptr, qkv, 8192, 2304, 768);

  // sliding-window attention -> attn (bf16, [B*T][768] head-concat layout)
  attn_k<<<8 * 12 * 16, 256, 0, stream>>>(qkv, attn);

  // x2 = x + attn @ Wproj + b_proj   (fp32 out) — m97 structure (N=768)
  gemm_bt<true,false,true,true><<<64 * 6, 256, 0, stream>>>(attn, WprojT, b_proj, x, x2, 8192, 768, 768);

  // h2 = rmsnorm(x2, g2)
  rmsnorm_k<<<2048, 256, 0, stream>>>(x2, g2, h2);

  // ffa = gelu(h2 @ Wff1 + b_ff1)   (bf16 out, M=8192, N=3072, K=768) — 256x256
  gemm256<true,true,false><<<32 * 12, 512, 0, stream>>>(h2, Wff1T, b_ff1, ffa, 8192, 3072, 768);

  // out = x2 + ffa @ Wff2 + b_ff2   (fp32, M=8192, N=768, K=3072) — m97 structure
  gemm_bt<true,false,true,true><<<64 * 6, 256, 0, stream>>>(ffa, Wff2T, b_ff2, x2, out, 8192, 768, 3072);

  // aux scalar
  aux_k<<<1, 64, 0, stream>>>(out + 6291456);
}

// Round 5
// 228.879 us; speedup vs baseline: 1.2039x; 1.2039x over previous
//
#include <hip/hip_runtime.h>
#include <cstdint>

#define DEVI __device__ __forceinline__

typedef __bf16 bf16x8 __attribute__((ext_vector_type(8)));
typedef float  f32x4  __attribute__((ext_vector_type(4)));

DEVI unsigned short f2b(float f){
  unsigned u = __builtin_bit_cast(unsigned, f);
  unsigned r = u + 0x7FFF + ((u >> 16) & 1);
  return (unsigned short)(r >> 16);
}
DEVI float b2f(unsigned short s){
  unsigned u = ((unsigned)s) << 16;
  return __builtin_bit_cast(float, u);
}
DEVI float gelu_f(float x){
  float u = 0.7978845608028654f * (x + 0.044715f * x * x * x);
  float e = __expf(2.0f * u);
  return x * (1.0f - 1.0f / (e + 1.0f));   // == 0.5x(1+tanh(u)), safe at e->inf / e->0
}
DEVI void gl_lds16(const unsigned short* g, unsigned short* l){
  __builtin_amdgcn_global_load_lds(
      (const __attribute__((address_space(1))) unsigned int*)g,
      (__attribute__((address_space(3))) unsigned int*)l, 16, 0, 0);
}

// ---------------- weight transpose + fp32->bf16: in[R][C] f32 -> out[C][R] bf16 ----
__global__ __launch_bounds__(256)
void transpose_f2b(const float* __restrict__ in, unsigned short* __restrict__ out,
                   int R, int C)
{
  __shared__ float tile[32][33];
  int nbx = C >> 5;
  int bx = blockIdx.x % nbx, by = blockIdx.x / nbx;
  int c0 = bx << 5, r0 = by << 5;
  int tx = threadIdx.x & 31, ty = threadIdx.x >> 5;   // 32 x 8
  #pragma unroll
  for (int j = 0; j < 32; j += 8)
    tile[ty + j][tx] = in[(size_t)(r0 + ty + j) * C + c0 + tx];
  __syncthreads();
  #pragma unroll
  for (int j = 0; j < 32; j += 8)
    out[(size_t)(c0 + ty + j) * R + r0 + tx] = f2b(tile[tx][ty + j]);
}

// ---------------- RMSNorm: x f32 [rows][768] -> out bf16, 1 wave per row ----------
__global__ __launch_bounds__(256)
void rmsnorm_k(const float* __restrict__ x, const float* __restrict__ g,
               unsigned short* __restrict__ out)
{
  int wid = threadIdx.x >> 6, lane = threadIdx.x & 63;
  size_t row = (size_t)blockIdx.x * 4 + wid;
  const float* xr = x + row * 768;
  float4 v[3];
  float ss = 0.0f;
  #pragma unroll
  for (int c = 0; c < 3; c++){
    v[c] = *(const float4*)&xr[lane * 4 + c * 256];
    ss += v[c].x * v[c].x + v[c].y * v[c].y + v[c].z * v[c].z + v[c].w * v[c].w;
  }
  #pragma unroll
  for (int o = 32; o >= 1; o >>= 1) ss += __shfl_xor(ss, o);
  float rs = rsqrtf(ss * (1.0f / 768.0f) + 1e-6f);
  #pragma unroll
  for (int c = 0; c < 3; c++){
    const float4 gv = *(const float4*)&g[lane * 4 + c * 256];
    ushort4 o4;
    o4.x = f2b(v[c].x * rs * gv.x);
    o4.y = f2b(v[c].y * rs * gv.y);
    o4.z = f2b(v[c].z * rs * gv.z);
    o4.w = f2b(v[c].w * rs * gv.w);
    *(ushort4*)&out[row * 768 + lane * 4 + c * 256] = o4;
  }
}

// ---------------- GEMM BMx128, BK=64, dbuf DMA, XOR-swizzled LDS ------------------
// C[M,N] = A[M,K](bf16) * Bt[N,K](bf16)^T, fused epilogue.
// 4 waves 2x2, per-wave (BM/2)x64. LDS = 2 x (BM+128)x64 bf16:
//   BM=128 -> 64 KB (2 blocks/CU), BM=64 -> 48 KB (3 blocks/CU).
// Swizzle: LDS[row][slot(16B)] holds global slot^(row&7) (linear DMA dest,
// inverse-swizzled per-lane source; read side applies same XOR) -> conflict-free.
// Pipeline: stage tile t+1 at top of tile t; ONE vmcnt(0)+barrier per tile.
// Requires M%BM==0, N%128==0, K%64==0, grid%8==0.
template<int BM, bool BIAS, bool GELU_, bool RES, bool OUTF32>
__global__ __launch_bounds__(256, BM == 64 ? 3 : 2)
void gemm_db(const unsigned short* __restrict__ A, const unsigned short* __restrict__ Bt,
             const float* __restrict__ bias, const float* __restrict__ res,
             void* __restrict__ outp, int M, int N, int K)
{
  constexpr int MI = BM / 32;             // m-frags per wave
  constexpr int AL = (BM * 8) / 256;      // A-stage instrs per wave
  __shared__ unsigned short sm[2][(BM + 128) * 64];

  int tid = threadIdx.x, wid = tid >> 6, lane = tid & 63;
  int la = lane & 15, hi = lane >> 4;
  int wm = wid >> 1, wn = wid & 1;        // 2x2 waves
  int tiles_n = N >> 7;
  int bid = blockIdx.x;
  bid = (bid & 7) * (gridDim.x >> 3) + (bid >> 3);   // XCD-aware swizzle
  int m0 = (bid / tiles_n) * BM, n0 = (bid % tiles_n) << 7;
  int NT = K >> 6;

  f32x4 acc[MI][4] = {};

  auto stage = [&](unsigned short* buf, int kt){
    #pragma unroll
    for (int l = 0; l < AL; l++){
      int cb  = wid * (BM * 2) + l * 64;          // wave-uniform chunk base
      int idx = cb + lane;
      int row = idx >> 3, slot = idx & 7, sl2 = slot ^ (row & 7);
      gl_lds16(A + (size_t)(m0 + row) * K + kt + sl2 * 8, buf + cb * 8);
    }
    #pragma unroll
    for (int l = 0; l < 4; l++){
      int cb  = wid * 256 + l * 64;
      int idx = cb + lane;
      int row = idx >> 3, slot = idx & 7, sl2 = slot ^ (row & 7);
      gl_lds16(Bt + (size_t)(n0 + row) * K + kt + sl2 * 8, buf + BM * 64 + cb * 8);
    }
  };

  stage(sm[0], 0);
  asm volatile("s_waitcnt vmcnt(0)" ::: "memory");
  __builtin_amdgcn_s_barrier();

  for (int t = 0; t < NT; t++){
    const unsigned short* As = sm[t & 1];
    const unsigned short* Bs = sm[t & 1] + BM * 64;

    if (t + 1 < NT) stage(sm[(t + 1) & 1], (t + 1) << 6);

    bf16x8 afr[MI][2], bfr[4][2];
    #pragma unroll
    for (int mm = 0; mm < MI; mm++)
      #pragma unroll
      for (int kk = 0; kk < 2; kk++){
        int r = wm * (BM / 2) + mm * 16 + la;
        afr[mm][kk] = *(const bf16x8*)&As[r * 64 + (((kk * 4 + hi) ^ (r & 7))) * 8];
      }
    #pragma unroll
    for (int nn = 0; nn < 4; nn++)
      #pragma unroll
      for (int kk = 0; kk < 2; kk++){
        int r = wn * 64 + nn * 16 + la;
        bfr[nn][kk] = *(const bf16x8*)&Bs[r * 64 + (((kk * 4 + hi) ^ (r & 7))) * 8];
      }
    #pragma unroll
    for (int mm = 0; mm < MI; mm++)
      #pragma unroll
      for (int nn = 0; nn < 4; nn++)
        #pragma unroll
        for (int kk = 0; kk < 2; kk++)
          acc[mm][nn] = __builtin_amdgcn_mfma_f32_16x16x32_bf16(
              afr[mm][kk], bfr[nn][kk], acc[mm][nn], 0, 0, 0);

    asm volatile("s_waitcnt vmcnt(0)" ::: "memory");   // own DMA (tile t+1) landed
    __builtin_amdgcn_s_barrier();                      // all waves' reads+DMA done
  }

  float* outF = (float*)outp;
  unsigned short* outB = (unsigned short*)outp;
  #pragma unroll
  for (int mm = 0; mm < MI; mm++){
    int rowb = m0 + wm * (BM / 2) + mm * 16 + hi * 4;
    #pragma unroll
    for (int nn = 0; nn < 4; nn++){
      int col = n0 + wn * 64 + nn * 16 + la;
      float bv = BIAS ? bias[col] : 0.0f;
      #pragma unroll
      for (int r = 0; r < 4; r++){
        float val = acc[mm][nn][r] + bv;
        if (GELU_) val = gelu_f(val);
        if (RES)   val += res[(size_t)(rowb + r) * N + col];
        size_t o = (size_t)(rowb + r) * N + col;
        if (OUTF32) outF[o] = val;
        else        outB[o] = f2b(val);
      }
    }
  }
}

// ---------------- sliding-window causal attention, W=64, D=64, MFMA tile ----------
__global__ __launch_bounds__(256)
void attn_k(const unsigned short* __restrict__ qkv, unsigned short* __restrict__ attn)
{
  __shared__ unsigned short Qs[64 * 72];       // stride 72: b128 reads at 8-way min
  __shared__ unsigned short Ks[128 * 72];
  __shared__ unsigned short Vt[64 * 136];      // V^T [d][s], stride 136
  __shared__ unsigned short Ps[4][16 * 136];   // per-wave P rows

  int tid = threadIdx.x, wid = tid >> 6, lane = tid & 63;
  int la = lane & 15, hi = lane >> 4;
  int blk = blockIdx.x;
  blk = (blk & 7) * (gridDim.x >> 3) + (blk >> 3);   // XCD swizzle (1536 % 8 == 0)
  int tile = blk & 15, hb = blk >> 4;
  int h = hb % 12, b = hb / 12;
  int t0 = tile << 6;

  const unsigned short* qbase = qkv + (size_t)(b * 1024) * 2304 + h * 64;

  // ---- stage Q: 64 rows x 8 chunks of 8 bf16
  #pragma unroll
  for (int r = 0; r < 2; r++){
    int idx = tid + r * 256;
    int row = idx >> 3, ch = idx & 7;
    uint4 v = *(const uint4*)(qbase + (size_t)(t0 + row) * 2304 + ch * 8);
    *(uint4*)&Qs[row * 72 + ch * 8] = v;
  }
  // ---- stage K: 128 rows (clamped at s_global<0; masked later)
  #pragma unroll
  for (int r = 0; r < 4; r++){
    int idx = tid + r * 256;
    int row = idx >> 3, ch = idx & 7;
    int sg = t0 - 64 + row; sg = sg < 0 ? 0 : sg;
    uint4 v = *(const uint4*)(qbase + 768 + (size_t)sg * 2304 + ch * 8);
    *(uint4*)&Ks[row * 72 + ch * 8] = v;
  }
  // ---- stage V transposed (s-major lane assignment -> 2-way LDS writes)
  #pragma unroll
  for (int r = 0; r < 4; r++){
    int idx = tid + r * 256;
    int s = idx & 127, ch = idx >> 7;
    int sg = t0 - 64 + s; sg = sg < 0 ? 0 : sg;
    uint4 v = *(const uint4*)(qbase + 1536 + (size_t)sg * 2304 + ch * 8);
    unsigned short tmp[8];
    *(uint4*)tmp = v;
    #pragma unroll
    for (int j = 0; j < 8; j++)
      Vt[(ch * 8 + j) * 136 + s] = tmp[j];
  }
  __syncthreads();

  // ---- S = Q K^T for 16 own rows x 128 cols (8 col-fragments x 2 k-steps)
  f32x4 sc[8];
  #pragma unroll
  for (int sj = 0; sj < 8; sj++) sc[sj] = (f32x4){0.f, 0.f, 0.f, 0.f};
  #pragma unroll
  for (int kk = 0; kk < 2; kk++){
    bf16x8 aq = *(const bf16x8*)&Qs[(wid * 16 + la) * 72 + kk * 32 + hi * 8];
    #pragma unroll
    for (int sj = 0; sj < 8; sj++){
      bf16x8 bk = *(const bf16x8*)&Ks[(sj * 16 + la) * 72 + kk * 32 + hi * 8];
      sc[sj] = __builtin_amdgcn_mfma_f32_16x16x32_bf16(aq, bk, sc[sj], 0, 0, 0);
    }
  }

  // ---- masked in-register softmax (row = wid*16 + hi*4 + r2, col = sj*16 + la)
  float inv[4];
  #pragma unroll
  for (int r2 = 0; r2 < 4; r2++){
    int row = wid * 16 + hi * 4 + r2;
    float mx = -1e30f;
    #pragma unroll
    for (int sj = 0; sj < 8; sj++){
      int sl = sj * 16 + la;
      bool valid = (sl >= row + 1) && (sl <= row + 64) && (t0 - 64 + sl >= 0);
      float sv = valid ? sc[sj][r2] * 0.125f : -1e30f;
      sc[sj][r2] = sv;
      mx = fmaxf(mx, sv);
    }
    #pragma unroll
    for (int o = 8; o >= 1; o >>= 1) mx = fmaxf(mx, __shfl_xor(mx, o));
    float sum = 0.0f;
    #pragma unroll
    for (int sj = 0; sj < 8; sj++){
      float p = __expf(sc[sj][r2] - mx);
      sc[sj][r2] = p;
      sum += p;
    }
    #pragma unroll
    for (int o = 8; o >= 1; o >>= 1) sum += __shfl_xor(sum, o);
    inv[r2] = 1.0f / sum;
  }

  // ---- P -> LDS (bf16), per-wave region
  unsigned short* myP = Ps[wid];
  #pragma unroll
  for (int sj = 0; sj < 8; sj++)
    #pragma unroll
    for (int r2 = 0; r2 < 4; r2++)
      myP[(hi * 4 + r2) * 136 + sj * 16 + la] = f2b(sc[sj][r2]);

  __syncthreads();

  // ---- O = P V  (A = P[16x128], B^T = Vt[64x128], 4 n-frags x 4 k-steps)
  f32x4 oacc[4];
  #pragma unroll
  for (int nj = 0; nj < 4; nj++) oacc[nj] = (f32x4){0.f, 0.f, 0.f, 0.f};
  #pragma unroll
  for (int ks = 0; ks < 4; ks++){
    bf16x8 ap = *(const bf16x8*)&myP[la * 136 + ks * 32 + hi * 8];
    #pragma unroll
    for (int nj = 0; nj < 4; nj++){
      bf16x8 bv = *(const bf16x8*)&Vt[(nj * 16 + la) * 136 + ks * 32 + hi * 8];
      oacc[nj] = __builtin_amdgcn_mfma_f32_16x16x32_bf16(ap, bv, oacc[nj], 0, 0, 0);
    }
  }

  // ---- write O (bf16, head-concat layout), scaled by 1/rowsum
  unsigned short* obase = attn + (size_t)(b * 1024 + t0) * 768 + h * 64;
  #pragma unroll
  for (int nj = 0; nj < 4; nj++)
    #pragma unroll
    for (int r2 = 0; r2 < 4; r2++){
      int row = wid * 16 + hi * 4 + r2;
      obase[(size_t)row * 768 + nj * 16 + la] = f2b(oacc[nj][r2] * inv[r2]);
    }
}

__global__ void aux_k(float* p){ if (threadIdx.x == 0) p[0] = 0.0f; }

// ----------------------------------------------------------------------------------
extern "C" void kernel_launch(void* const* d_in, const int* in_sizes, int n_in,
                              void* d_out, int out_size, void* d_ws, size_t ws_size,
                              hipStream_t stream)
{
  const float* x      = (const float*)d_in[0];
  const float* w_q    = (const float*)d_in[1];
  const float* w_k    = (const float*)d_in[2];
  const float* w_v    = (const float*)d_in[3];
  const float* w_proj = (const float*)d_in[4];
  const float* b_proj = (const float*)d_in[5];
  const float* w_ff1  = (const float*)d_in[6];
  const float* b_ff1  = (const float*)d_in[7];
  const float* w_ff2  = (const float*)d_in[8];
  const float* b_ff2  = (const float*)d_in[9];
  const float* g1     = (const float*)d_in[10];
  const float* g2     = (const float*)d_in[11];
  float* out = (float*)d_out;

  char* ws = (char*)d_ws;
  size_t off = 0;
  auto alloc = [&](size_t bytes){ size_t r = off; off += (bytes + 255) & ~(size_t)255; return r; };
  const size_t BT = 8 * 1024;  // 8192 rows

  unsigned short* h     = (unsigned short*)(ws + alloc(BT * 768 * 2));   // reused for attn out
  unsigned short* qkv   = (unsigned short*)(ws + alloc(BT * 3072 * 2));  // reused for ffa
  float*          x2    = (float*)         (ws + alloc(BT * 768 * 4));
  unsigned short* h2    = (unsigned short*)(ws + alloc(BT * 768 * 2));
  unsigned short* WqkvT = (unsigned short*)(ws + alloc(2304 * 768 * 2));
  unsigned short* WprojT= (unsigned short*)(ws + alloc(768 * 768 * 2));
  unsigned short* Wff1T = (unsigned short*)(ws + alloc(3072 * 768 * 2));
  unsigned short* Wff2T = (unsigned short*)(ws + alloc(768 * 3072 * 2));
  unsigned short* attn  = h;     // h dead after QKV GEMM
  unsigned short* ffa   = qkv;   // qkv dead after attention

  // weights -> bf16, transposed to [N][K]
  transpose_f2b<<<576, 256, 0, stream>>>(w_q,    WqkvT,             768, 768);
  transpose_f2b<<<576, 256, 0, stream>>>(w_k,    WqkvT + 768 * 768, 768, 768);
  transpose_f2b<<<576, 256, 0, stream>>>(w_v,    WqkvT + 1536 * 768,768, 768);
  transpose_f2b<<<576, 256, 0, stream>>>(w_proj, WprojT,            768, 768);
  transpose_f2b<<<24 * 96, 256, 0, stream>>>(w_ff1, Wff1T, 768, 3072);
  transpose_f2b<<<96 * 24, 256, 0, stream>>>(w_ff2, Wff2T, 3072, 768);

  // h = rmsnorm(x, g1)
  rmsnorm_k<<<2048, 256, 0, stream>>>(x, g1, h);

  // qkv = h @ [Wq|Wk|Wv]   (M=8192, N=2304, K=768), bf16 out
  gemm_db<128,false,false,false,false><<<64 * 18, 256, 0, stream>>>(h, WqkvT, nullptr, nullptr, qkv, 8192, 2304, 768);

  // sliding-window attention -> attn (bf16, [B*T][768] head-concat layout)
  attn_k<<<8 * 12 * 16, 256, 0, stream>>>(qkv, attn);

  // x2 = x + attn @ Wproj + b_proj   (fp32 out), BM=64 -> grid 768 (3 blocks/CU)
  gemm_db<64,true,false,true,true><<<128 * 6, 256, 0, stream>>>(attn, WprojT, b_proj, x, x2, 8192, 768, 768);

  // h2 = rmsnorm(x2, g2)
  rmsnorm_k<<<2048, 256, 0, stream>>>(x2, g2, h2);

  // ffa = gelu(h2 @ Wff1 + b_ff1)   (bf16 out, M=8192, N=3072, K=768)
  gemm_db<128,true,true,false,false><<<64 * 24, 256, 0, stream>>>(h2, Wff1T, b_ff1, nullptr, ffa, 8192, 3072, 768);

  // out = x2 + ffa @ Wff2 + b_ff2   (fp32, M=8192, N=768, K=3072), BM=64
  gemm_db<64,true,false,true,true><<<128 * 6, 256, 0, stream>>>(ffa, Wff2T, b_ff2, x2, out, 8192, 768, 3072);

  // aux scalar
  aux_k<<<1, 64, 0, stream>>>(out + 6291456);
}